// Round 6
// baseline (300.221 us; speedup 1.0000x reference)
//
#include <hip/hip_runtime.h>
#include <math.h>
#include <stdint.h>
#include <stddef.h>

// ---------------------------------------------------------------------------
// SelfAttention forward, fp32 I/O, bf16 MFMA internally.
// Round 11 (resubmit; previous bench died on container acquisition).
// v9 structure, TLP-focused. Attention blocks split to 64 q rows
// (grid 64x32 = 2048 blocks, 8/CU available); single-buffered 16 KB K/V LDS
// (10-block LDS cap) with reg-staged prefetch; per-wave state ~50 VGPR so
// the HW can hold 8 waves/SIMD. Round-4's preload-all + LB(,2) reverted
// (compiler sank the preloads; occupancy fell 33->21%).
// ---------------------------------------------------------------------------

#define SEQ    2048
#define NB     4
#define E_DIM  1024
#define N1     3072
#define M_TOK  8192
#define NHEAD  16
#define DHEAD  64

typedef __attribute__((ext_vector_type(4))) float    floatx4;
typedef __attribute__((ext_vector_type(8))) short    shortx8;
typedef __attribute__((ext_vector_type(4))) short    shortx4;
typedef __attribute__((ext_vector_type(4))) unsigned short ushortx4;

#if __has_builtin(__builtin_amdgcn_exp2f)
#define EXP2(x) __builtin_amdgcn_exp2f(x)
#else
#define EXP2(x) __expf((x) * 0.6931471805599453f)
#endif

// K=16 bf16 MFMA: A,B = 4x bf16 (2 VGPRs), C/D = 4x f32. A layout
// (row=lane&15, k=quad*4+i) is the exact transpose of the 16x16 C/D layout.
#define MFMA_K16(a, b, c) \
    __builtin_amdgcn_mfma_f32_16x16x16bf16_1k((a), (b), (c), 0, 0, 0)

__device__ __forceinline__ unsigned short f2bf(float f) {
    union { float f; unsigned u; } v; v.f = f;
    unsigned r = (v.u + 0x7FFFu + ((v.u >> 16) & 1u)) >> 16;  // RNE
    return (unsigned short)r;
}
__device__ __forceinline__ unsigned fbits(float f) {
    union { float f; unsigned u; } v; v.f = f; return v.u;
}

__device__ __forceinline__ void gl_lds16(const void* g, void* l) {
    __builtin_amdgcn_global_load_lds(
        (const __attribute__((address_space(1))) unsigned int*)g,
        (__attribute__((address_space(3))) unsigned int*)l, 16, 0, 0);
}

// --------------------------- fp32 -> bf16 convert ---------------------------
__global__ __launch_bounds__(256) void cvt_bf16(
    const float* __restrict__ in, unsigned short* __restrict__ out)
{
    const size_t i = ((size_t)blockIdx.x * 256 + threadIdx.x) * 8;
    float4 a = *(const float4*)(in + i);
    float4 b = *(const float4*)(in + i + 4);
    ushortx4 o0 = { f2bf(a.x), f2bf(a.y), f2bf(a.z), f2bf(a.w) };
    ushortx4 o1 = { f2bf(b.x), f2bf(b.y), f2bf(b.z), f2bf(b.w) };
    *(ushortx4*)(out + i)     = o0;
    *(ushortx4*)(out + i + 4) = o1;
}

// -------------------- fp32 [K][N] -> bf16 transposed [N][K] -----------------
__global__ __launch_bounds__(256) void cvt_transpose(
    const float* __restrict__ W, unsigned short* __restrict__ Wt, int K, int N)
{
    __shared__ unsigned short tile[32][33];
    const int tx = threadIdx.x, ty = threadIdx.y;   // (32, 8)
    const int n0 = blockIdx.x * 32, k0 = blockIdx.y * 32;
#pragma unroll
    for (int r = 0; r < 4; ++r) {
        const int k = ty + r * 8;
        tile[tx][k] = f2bf(W[(size_t)(k0 + k) * N + n0 + tx]);
    }
    __syncthreads();
#pragma unroll
    for (int r = 0; r < 4; ++r) {
        const int n = ty + r * 8;
        Wt[(size_t)(n0 + n) * K + k0 + tx] = tile[n][tx];
    }
}

// --------------------------- bf16 MFMA GEMM --------------------------------
// C[M,N] = A[M,K](bf16) @ Bt[N,K](bf16, pre-transposed) + bias[N](f32).
// BK=64, single-buffered LDS (32 KB), XOR8 swizzle via pre-swizzled global
// source chunks (global_load_lds dest must stay linear) + swizzled ds_read.
// FUSE (gemm1 only): Q columns (col%192 < 64) pre-scaled by log2(e)/8 before
// bf16 store; V columns (col%192 >= 128) also written transposed into
// Vt[bh][d][s] (4 consecutive rows per lane -> packed 8B store).
template <bool OUT_BF16, bool FUSE>
__global__ __launch_bounds__(256) void gemm_bf16(
    const short* __restrict__ A, const short* __restrict__ Bt,
    const float* __restrict__ bias, void* __restrict__ Cout,
    unsigned short* __restrict__ Vt,
    int M, int N, int K)
{
    __shared__ short As[128 * 64];
    __shared__ short Bs[128 * 64];

    const int t    = threadIdx.x;
    const int lane = t & 63, w = t >> 6;
    const int quad = lane >> 4, l15 = lane & 15;
    const int bm = blockIdx.y * 128, bn = blockIdx.x * 128;
    const int m0w = (w >> 1) * 64, n0w = (w & 1) * 64;

    // staging: thread t owns row t>>3 (+32 per round), 16B chunk t&7.
    // Global chunk pre-swizzled by row&7; LDS dest linear (t*16B per wave).
    const int srow   = t >> 3;            // 0..31
    const int schunk = t & 7;             // 16B chunk in 128B row
    const int gch    = schunk ^ (srow & 7);
    const short* Ag = A  + (size_t)(bm + srow) * K + gch * 8;
    const short* Bg = Bt + (size_t)(bn + srow) * K + gch * 8;
    short* Al = As + srow * 64 + schunk * 8;
    short* Bl = Bs + srow * 64 + schunk * 8;

    floatx4 acc[4][4];
#pragma unroll
    for (int i = 0; i < 4; ++i)
#pragma unroll
        for (int j = 0; j < 4; ++j) acc[i][j] = (floatx4)0.f;

    for (int k0 = 0; k0 < K; k0 += 64) {
        __syncthreads();
#pragma unroll
        for (int r = 0; r < 4; ++r) {
            gl_lds16(Ag + (size_t)(r * 32) * K + k0, Al + r * 32 * 64);
            gl_lds16(Bg + (size_t)(r * 32) * K + k0, Bl + r * 32 * 64);
        }
        __syncthreads();

#pragma unroll
        for (int kk = 0; kk < 2; ++kk) {
            shortx8 af[4], bf[4];
#pragma unroll
            for (int mi = 0; mi < 4; ++mi)
                af[mi] = *(const shortx8*)(As + (m0w + mi * 16 + l15) * 64
                                           + (((kk * 4 + quad) ^ (l15 & 7)) * 8));
#pragma unroll
            for (int ni = 0; ni < 4; ++ni)
                bf[ni] = *(const shortx8*)(Bs + (n0w + ni * 16 + l15) * 64
                                           + (((kk * 4 + quad) ^ (l15 & 7)) * 8));
#pragma unroll
            for (int mi = 0; mi < 4; ++mi)
#pragma unroll
                for (int ni = 0; ni < 4; ++ni)
                    acc[mi][ni] = __builtin_amdgcn_mfma_f32_16x16x32_bf16(
                        af[mi], bf[ni], acc[mi][ni], 0, 0, 0);
        }
    }

    float bv[4];
#pragma unroll
    for (int ni = 0; ni < 4; ++ni) bv[ni] = bias[bn + n0w + ni * 16 + l15];

#pragma unroll
    for (int ni = 0; ni < 4; ++ni) {
        const int col   = bn + n0w + ni * 16 + l15;
        const int cm    = col % 192;      // wave-uniform block (no divergence)
        const int vhead = col / 192;
#pragma unroll
        for (int mi = 0; mi < 4; ++mi) {
            const int row0 = bm + m0w + mi * 16 + quad * 4;
            float v[4];
#pragma unroll
            for (int r = 0; r < 4; ++r) v[r] = acc[mi][ni][r] + bv[ni];
            if (OUT_BF16) {
                if (FUSE && cm < DHEAD) {
#pragma unroll
                    for (int r = 0; r < 4; ++r) v[r] *= 0.18033688011112042f;  // log2(e)/8
                }
                unsigned short* H = (unsigned short*)Cout;
#pragma unroll
                for (int r = 0; r < 4; ++r)
                    H[(size_t)(row0 + r) * N + col] = f2bf(v[r]);
                if (FUSE && cm >= 2 * DHEAD) {
                    const int nb = row0 >> 11;       // batch
                    const int s  = row0 & 2047;
                    const int d  = cm - 2 * DHEAD;
                    ushortx4 pk = { f2bf(v[0]), f2bf(v[1]), f2bf(v[2]), f2bf(v[3]) };
                    *(ushortx4*)(Vt + ((size_t)(nb * NHEAD + vhead) * DHEAD + d) * SEQ + s) = pk;
                }
            } else {
                float* C = (float*)Cout;
#pragma unroll
                for (int r = 0; r < 4; ++r)
                    C[(size_t)(row0 + r) * N + col] = v[r];
            }
        }
    }
}

// ------------------------- MFMA flash attention v11 -------------------------
// 256 thr = 4 waves; wave w owns q rows q0+w*16 .. +15, full d=64.
// Grid (64 bh, 32 q-chunks) = 2048 blocks -> 8 available blocks/CU; LDS cut
// to 16 KB (single-buffered K/V) so residency is grid-limited, not LDS-
// limited. Reg-staged prefetch: next tile's global loads issue right after
// the "ready" barrier, landing during compute; ds_write after the "done"
// barrier. Softmax P stays in registers (16x16 C/D <-> K=16 A-frag duality).
__global__ __launch_bounds__(256, 4) void attn_mfma(
    const short* __restrict__ h, const short* __restrict__ Vt,
    unsigned short* __restrict__ att)
{
    __shared__ short Ks[64 * 64];       // [kv][d], XOR8 16B-chunk swizzle
    __shared__ short Vs[64 * 64];       // [d][kv], XOR8 8B-chunk swizzle

    const int t    = threadIdx.x;
    const int lane = t & 63, w = t >> 6;
    const int quad = lane >> 4, l15 = lane & 15;
    const int r7   = l15 & 7;
    const int bh = blockIdx.x, n = bh >> 4, head = bh & 15;
    const int q0 = blockIdx.y * 64 + w * 16;

    const short* hQ  = h + (size_t)n * SEQ * N1 + head * (3 * DHEAD);
    const short* hK  = hQ + DHEAD;
    const short* Vtb = Vt + (size_t)bh * DHEAD * SEQ;

    // staging: thread t owns row t>>2, 16B chunks (t&3)*2 and +1 (K and V)
    const int srow = t >> 2;
    const int sc0  = (t & 3) * 2;
    const int sk   = srow & 7;
    const short* gK = hK  + (size_t)srow * N1  + sc0 * 8;
    const short* gV = Vtb + (size_t)srow * SEQ + sc0 * 8;
    const int oL0 = srow * 64 + ((sc0    ) ^ sk) * 8;
    const int oL1 = srow * 64 + ((sc0 + 1) ^ sk) * 8;

    // Q fragments: 16 rows per wave, hoisted once
    shortx8 qf[2];
#pragma unroll
    for (int kt = 0; kt < 2; ++kt)
        qf[kt] = *(const shortx8*)(hQ + (size_t)(q0 + l15) * N1 + kt * 32 + quad * 8);

    floatx4 O[4];                       // d-tiles, full d per wave
    float lsum = 0.f;                   // row-sum partial: q = q0 + l15
#pragma unroll
    for (int dt = 0; dt < 4; ++dt) O[dt] = (floatx4)0.f;

    const int NT = SEQ / 64;

    // prologue: tile 0 into regs
    int4 ka = *(const int4*)gK, kb = *(const int4*)(gK + 8);
    int4 va = *(const int4*)gV, vb = *(const int4*)(gV + 8);
    gK += (size_t)64 * N1; gV += 64;

    for (int it = 0; it < NT; ++it) {
        __syncthreads();                // prev tile's reads done; LDS free
        *(int4*)(Ks + oL0) = ka;
        *(int4*)(Ks + oL1) = kb;
        *(int4*)(Vs + oL0) = va;
        *(int4*)(Vs + oL1) = vb;
        __syncthreads();                // tile ready

        if (it + 1 < NT) {              // issue next-tile global loads early;
            ka = *(const int4*)gK;      // latency hides under compute below
            kb = *(const int4*)(gK + 8);
            va = *(const int4*)gV;
            vb = *(const int4*)(gV + 8);
            gK += (size_t)64 * N1; gV += 64;
        }

        __builtin_amdgcn_s_setprio(1);
#pragma unroll
        for (int sl = 0; sl < 4; ++sl) {
            // K fragments (b128, swizzled)
            const short* krow = Ks + (sl * 16 + l15) * 64;
            shortx8 kf0 = *(const shortx8*)(krow + ((quad ^ r7) * 8));
            shortx8 kf1 = *(const shortx8*)(krow + (((quad ^ 4) ^ r7) * 8));
            // V fragments for K=16 PV: B[k=kv=quad*4+i][col=d=l15] contiguous 8B
            shortx4 vf[4];
#pragma unroll
            for (int dt = 0; dt < 4; ++dt)
                vf[dt] = *(const shortx4*)(Vs + (dt * 16 + l15) * 64
                                           + (((sl * 4 + quad) ^ (r7 << 1)) << 2));

            // S^T then exp2 then pack: registers become the PV A-fragment
            floatx4 s = __builtin_amdgcn_mfma_f32_16x16x32_bf16(
                kf0, qf[0], (floatx4)0.f, 0, 0, 0);
            s = __builtin_amdgcn_mfma_f32_16x16x32_bf16(
                kf1, qf[1], s, 0, 0, 0);
            const float p0 = EXP2(s[0]);
            const float p1 = EXP2(s[1]);
            const float p2 = EXP2(s[2]);
            const float p3 = EXP2(s[3]);
            lsum += (p0 + p1) + (p2 + p3);
            union { uint2 u; shortx4 v; } cv;
            cv.u.x = __builtin_amdgcn_perm(fbits(p1), fbits(p0), 0x07060302u);
            cv.u.y = __builtin_amdgcn_perm(fbits(p3), fbits(p2), 0x07060302u);
            const shortx4 pa = cv.v;

            // O += P @ V (K=16; P already in A-fragment layout)
#pragma unroll
            for (int dt = 0; dt < 4; ++dt)
                O[dt] = MFMA_K16(pa, vf[dt], O[dt]);
        }
        __builtin_amdgcn_s_setprio(0);
    }

    // row sums: reduce across quads; sum for q=q0+j then lives at l15=j.
    lsum += __shfl_xor(lsum, 16);
    lsum += __shfl_xor(lsum, 32);

    // epilogue: normalize and store (O row = quad*4+r, col d = l15)
    const size_t obase = ((size_t)n * SEQ + q0) * E_DIM + head * DHEAD;
#pragma unroll
    for (int r = 0; r < 4; ++r) {
        const float inv = 1.f / __shfl(lsum, quad * 4 + r);
        const size_t row = obase + (size_t)(quad * 4 + r) * E_DIM;
#pragma unroll
        for (int dt = 0; dt < 4; ++dt)
            att[row + dt * 16 + l15] = f2bf(O[dt][r] * inv);
    }
}

// ------------------------------- launch ------------------------------------
extern "C" void kernel_launch(void* const* d_in, const int* in_sizes, int n_in,
                              void* d_out, int out_size, void* d_ws, size_t ws_size,
                              hipStream_t stream)
{
    const float* x  = (const float*)d_in[0];
    const float* W1 = (const float*)d_in[1];
    const float* b1 = (const float*)d_in[2];
    const float* W2 = (const float*)d_in[3];
    const float* b2 = (const float*)d_in[4];
    float* out = (float*)d_out;

    char* ws = (char*)d_ws;
    unsigned short* x_bf  = (unsigned short*)(ws);                    // 16 MB
    unsigned short* W1t   = (unsigned short*)(ws + (16u << 20));      //  6 MB
    unsigned short* W2t   = (unsigned short*)(ws + (22u << 20));      //  2 MB
    unsigned short* h_bf  = (unsigned short*)(ws + (24u << 20));      // 48 MB
    unsigned short* attb  = (unsigned short*)(ws + (72u << 20));      // 16 MB
    unsigned short* Vtw   = (unsigned short*)(ws + (88u << 20));      // 16 MB

    cvt_bf16<<<dim3((M_TOK * E_DIM) / (256 * 8)), 256, 0, stream>>>(x, x_bf);
    cvt_transpose<<<dim3(N1 / 32, E_DIM / 32), dim3(32, 8), 0, stream>>>(W1, W1t, E_DIM, N1);
    cvt_transpose<<<dim3(E_DIM / 32, E_DIM / 32), dim3(32, 8), 0, stream>>>(W2, W2t, E_DIM, E_DIM);

    // h = x@W1+b1 (bf16; Q cols pre-scaled log2(e)/8; V cols also -> Vt transposed)
    gemm_bf16<true, true><<<dim3(N1 / 128, M_TOK / 128), 256, 0, stream>>>(
        (const short*)x_bf, (const short*)W1t, b1, h_bf, Vtw, M_TOK, N1, E_DIM);

    attn_mfma<<<dim3(NB * NHEAD, SEQ / 64), 256, 0, stream>>>(
        (const short*)h_bf, (const short*)Vtw, attb);

    gemm_bf16<false, false><<<dim3(E_DIM / 128, M_TOK / 128), 256, 0, stream>>>(
        (const short*)attb, (const short*)W2t, b2, out, nullptr, M_TOK, E_DIM, E_DIM);
}

// Round 7
// 266.223 us; speedup vs baseline: 1.1277x; 1.1277x over previous
//
#include <hip/hip_runtime.h>
#include <math.h>
#include <stdint.h>
#include <stddef.h>

// ---------------------------------------------------------------------------
// SelfAttention forward, fp32 I/O, bf16 MFMA internally.
// Round 12: attn reverted to v8 verbatim (round-2, 90.0 us measured; rounds
// 3-6 variations all regressed). GEMM upgraded to 2-deep pipelined double
// buffer: counted s_waitcnt vmcnt(8) + raw s_barrier (no full drain in the
// K-loop; the m97-style __syncthreads vmcnt(0) stall was the gemm limiter).
// ---------------------------------------------------------------------------

#define SEQ    2048
#define NB     4
#define E_DIM  1024
#define N1     3072
#define M_TOK  8192
#define NHEAD  16
#define DHEAD  64

typedef __attribute__((ext_vector_type(4))) float    floatx4;
typedef __attribute__((ext_vector_type(8))) short    shortx8;
typedef __attribute__((ext_vector_type(4))) short    shortx4;
typedef __attribute__((ext_vector_type(4))) unsigned short ushortx4;

#if __has_builtin(__builtin_amdgcn_exp2f)
#define EXP2(x) __builtin_amdgcn_exp2f(x)
#else
#define EXP2(x) __expf((x) * 0.6931471805599453f)
#endif

// K=16 bf16 MFMA: A,B = 4x bf16 (2 VGPRs), C/D = 4x f32. A layout
// (row=lane&15, k=quad*4+i) is the exact transpose of the 16x16 C/D layout.
#define MFMA_K16(a, b, c) \
    __builtin_amdgcn_mfma_f32_16x16x16bf16_1k((a), (b), (c), 0, 0, 0)

__device__ __forceinline__ unsigned short f2bf(float f) {
    union { float f; unsigned u; } v; v.f = f;
    unsigned r = (v.u + 0x7FFFu + ((v.u >> 16) & 1u)) >> 16;  // RNE
    return (unsigned short)r;
}
__device__ __forceinline__ unsigned fbits(float f) {
    union { float f; unsigned u; } v; v.f = f; return v.u;
}
__device__ __forceinline__ float bitsf(unsigned u) {
    union { unsigned u; float f; } v; v.u = u; return v.f;
}

__device__ __forceinline__ void gl_lds16(const void* g, void* l) {
    __builtin_amdgcn_global_load_lds(
        (const __attribute__((address_space(1))) unsigned int*)g,
        (__attribute__((address_space(3))) unsigned int*)l, 16, 0, 0);
}

// --------------------------- fp32 -> bf16 convert ---------------------------
__global__ __launch_bounds__(256) void cvt_bf16(
    const float* __restrict__ in, unsigned short* __restrict__ out)
{
    const size_t i = ((size_t)blockIdx.x * 256 + threadIdx.x) * 8;
    float4 a = *(const float4*)(in + i);
    float4 b = *(const float4*)(in + i + 4);
    ushortx4 o0 = { f2bf(a.x), f2bf(a.y), f2bf(a.z), f2bf(a.w) };
    ushortx4 o1 = { f2bf(b.x), f2bf(b.y), f2bf(b.z), f2bf(b.w) };
    *(ushortx4*)(out + i)     = o0;
    *(ushortx4*)(out + i + 4) = o1;
}

// -------------------- fp32 [K][N] -> bf16 transposed [N][K] -----------------
__global__ __launch_bounds__(256) void cvt_transpose(
    const float* __restrict__ W, unsigned short* __restrict__ Wt, int K, int N)
{
    __shared__ unsigned short tile[32][33];
    const int tx = threadIdx.x, ty = threadIdx.y;   // (32, 8)
    const int n0 = blockIdx.x * 32, k0 = blockIdx.y * 32;
#pragma unroll
    for (int r = 0; r < 4; ++r) {
        const int k = ty + r * 8;
        tile[tx][k] = f2bf(W[(size_t)(k0 + k) * N + n0 + tx]);
    }
    __syncthreads();
#pragma unroll
    for (int r = 0; r < 4; ++r) {
        const int n = ty + r * 8;
        Wt[(size_t)(n0 + n) * K + k0 + tx] = tile[n][tx];
    }
}

// --------------------------- bf16 MFMA GEMM --------------------------------
// C[M,N] = A[M,K](bf16) @ Bt[N,K](bf16, pre-transposed) + bias[N](f32).
// BM=BN=128, BK=64, DOUBLE-buffered LDS (64 KB), 2-deep prefetch pipeline:
//   iter t: vmcnt(8) [tile t landed; t+1 in flight] -> s_barrier (publish)
//           -> ds_read frags + 32 MFMA on buf[t] -> s_barrier (buf free)
//           -> global_load_lds tile t+2 into buf[t]
// No vmcnt(0) drain inside the loop (the round-3 version exposed full L2
// latency at every K-step via __syncthreads). XOR8 swizzle via pre-swizzled
// GLOBAL source chunks (gl_lds dest stays linear) + swizzled ds_read.
// FUSE (gemm1 only): Q columns (col%192 < 64) pre-scaled by log2(e)/8;
// V columns (col%192 >= 128) also stored transposed into Vt[bh][d][s].
template <bool OUT_BF16, bool FUSE>
__global__ __launch_bounds__(256) void gemm_bf16(
    const short* __restrict__ A, const short* __restrict__ Bt,
    const float* __restrict__ bias, void* __restrict__ Cout,
    unsigned short* __restrict__ Vt,
    int M, int N, int K)
{
    __shared__ short As[2][128 * 64];
    __shared__ short Bs[2][128 * 64];

    const int t    = threadIdx.x;
    const int lane = t & 63, w = t >> 6;
    const int quad = lane >> 4, l15 = lane & 15;
    const int bm = blockIdx.y * 128, bn = blockIdx.x * 128;
    const int m0w = (w >> 1) * 64, n0w = (w & 1) * 64;

    // staging: thread t owns row t>>3 (+32 per round), 16B chunk t&7.
    // Global chunk pre-swizzled by row&7; LDS dest linear (lane*16B per wave).
    const int srow   = t >> 3;            // 0..31
    const int schunk = t & 7;             // 16B chunk in 128B row
    const int gch    = schunk ^ (srow & 7);
    const short* Ag = A  + (size_t)(bm + srow) * K + gch * 8;
    const short* Bg = Bt + (size_t)(bn + srow) * K + gch * 8;
    const int sOff = srow * 64 + schunk * 8;   // shorts

    floatx4 acc[4][4];
#pragma unroll
    for (int i = 0; i < 4; ++i)
#pragma unroll
        for (int j = 0; j < 4; ++j) acc[i][j] = (floatx4)0.f;

    const int NK = K >> 6;     // K/64 K-steps

#define GEMM_STAGE(bufi, k0)                                                   \
    {                                                                          \
        _Pragma("unroll")                                                      \
        for (int r = 0; r < 4; ++r) {                                          \
            gl_lds16(Ag + (size_t)(r * 32) * K + (k0), &As[bufi][sOff + r * 32 * 64]); \
            gl_lds16(Bg + (size_t)(r * 32) * K + (k0), &Bs[bufi][sOff + r * 32 * 64]); \
        }                                                                      \
    }

    // prologue: tiles 0 and 1 in flight (16 outstanding loads)
    GEMM_STAGE(0, 0);
    GEMM_STAGE(1, 64);

    for (int kt = 0; kt < NK; ++kt) {
        const int buf = kt & 1;
        // wait for tile kt (8 newest = tile kt+1 may stay in flight)
        if (kt + 1 < NK) asm volatile("s_waitcnt vmcnt(8)" ::: "memory");
        else             asm volatile("s_waitcnt vmcnt(0)" ::: "memory");
        __builtin_amdgcn_sched_barrier(0);
        __builtin_amdgcn_s_barrier();          // publish tile kt to all waves
        __builtin_amdgcn_sched_barrier(0);

#pragma unroll
        for (int kk = 0; kk < 2; ++kk) {
            shortx8 af[4], bf[4];
#pragma unroll
            for (int mi = 0; mi < 4; ++mi)
                af[mi] = *(const shortx8*)(&As[buf][(m0w + mi * 16 + l15) * 64
                                           + (((kk * 4 + quad) ^ (l15 & 7)) * 8)]);
#pragma unroll
            for (int ni = 0; ni < 4; ++ni)
                bf[ni] = *(const shortx8*)(&Bs[buf][(n0w + ni * 16 + l15) * 64
                                           + (((kk * 4 + quad) ^ (l15 & 7)) * 8)]);
#pragma unroll
            for (int mi = 0; mi < 4; ++mi)
#pragma unroll
                for (int ni = 0; ni < 4; ++ni)
                    acc[mi][ni] = __builtin_amdgcn_mfma_f32_16x16x32_bf16(
                        af[mi], bf[ni], acc[mi][ni], 0, 0, 0);
        }

        __builtin_amdgcn_sched_barrier(0);
        __builtin_amdgcn_s_barrier();          // all waves done reading buf
        __builtin_amdgcn_sched_barrier(0);
        if (kt + 2 < NK) GEMM_STAGE(buf, (kt + 2) * 64);
    }
#undef GEMM_STAGE

    float bv[4];
#pragma unroll
    for (int ni = 0; ni < 4; ++ni) bv[ni] = bias[bn + n0w + ni * 16 + l15];

#pragma unroll
    for (int ni = 0; ni < 4; ++ni) {
        const int col   = bn + n0w + ni * 16 + l15;
        const int cm    = col % 192;      // wave-uniform block (no divergence)
        const int vhead = col / 192;
#pragma unroll
        for (int mi = 0; mi < 4; ++mi) {
            const int row0 = bm + m0w + mi * 16 + quad * 4;
            float v[4];
#pragma unroll
            for (int r = 0; r < 4; ++r) v[r] = acc[mi][ni][r] + bv[ni];
            if (OUT_BF16) {
                if (FUSE && cm < DHEAD) {
#pragma unroll
                    for (int r = 0; r < 4; ++r) v[r] *= 0.18033688011112042f;  // log2(e)/8
                }
                unsigned short* H = (unsigned short*)Cout;
#pragma unroll
                for (int r = 0; r < 4; ++r)
                    H[(size_t)(row0 + r) * N + col] = f2bf(v[r]);
                if (FUSE && cm >= 2 * DHEAD) {
                    const int nb = row0 >> 11;       // batch
                    const int s  = row0 & 2047;
                    const int d  = cm - 2 * DHEAD;
                    ushortx4 pk = { f2bf(v[0]), f2bf(v[1]), f2bf(v[2]), f2bf(v[3]) };
                    *(ushortx4*)(Vt + ((size_t)(nb * NHEAD + vhead) * DHEAD + d) * SEQ + s) = pk;
                }
            } else {
                float* C = (float*)Cout;
#pragma unroll
                for (int r = 0; r < 4; ++r)
                    C[(size_t)(row0 + r) * N + col] = v[r];
            }
        }
    }
}

// ------------------------- MFMA flash attention v8 --------------------------
// (verbatim round-2 version: 90.0 us measured; rounds 3-6 variants regressed)
// 256 thr = 4 independent waves; wave w owns q rows q0+w*32 .. +31, full d=64.
// Per 16-kv slab: S^T = mfma16x16x32(K,Q) -> exp2 -> pack bf16 in-lane; the
// packed regs ARE the A-fragment of mfma_16x16x16bf16_1k (layout duality), so
// PV needs no LDS P and no cross-lane. Row sums: extra K=16 MFMA vs ones.
// K/V staged in double-buffered LDS; ONE __syncthreads per 64-kv tile.
__global__ __launch_bounds__(256, 4) void attn_mfma(
    const short* __restrict__ h, const short* __restrict__ Vt,
    unsigned short* __restrict__ att)
{
    __shared__ short Ks[2][64 * 64];    // [kv][d], XOR8 16B-chunk swizzle
    __shared__ short Vs[2][64 * 64];    // [d][kv], XOR8 16B-chunk swizzle

    const int t    = threadIdx.x;
    const int lane = t & 63, w = t >> 6;
    const int quad = lane >> 4, l15 = lane & 15;
    const int r7   = l15 & 7;
    const int bh = blockIdx.x, n = bh >> 4, head = bh & 15;
    const int q0 = blockIdx.y * 128 + w * 32;

    const short* hQ  = h + (size_t)n * SEQ * N1 + head * (3 * DHEAD);
    const short* hK  = hQ + DHEAD;
    const short* Vtb = Vt + (size_t)bh * DHEAD * SEQ;

    // staging: thread t owns row t>>2, 16B chunks (t&3)*2 and +1 (K and V)
    const int srow = t >> 2;
    const int sc0  = (t & 3) * 2;
    const int sk   = srow & 7;
    const short* gK = hK  + (size_t)srow * N1  + sc0 * 8;
    const short* gV = Vtb + (size_t)srow * SEQ + sc0 * 8;
    const int oL0 = srow * 64 + ((sc0    ) ^ sk) * 8;
    const int oL1 = srow * 64 + ((sc0 + 1) ^ sk) * 8;

    // Q fragments: 32 rows per wave, hoisted once
    shortx8 qf[2][2];
#pragma unroll
    for (int qt = 0; qt < 2; ++qt)
#pragma unroll
        for (int kt = 0; kt < 2; ++kt)
            qf[qt][kt] = *(const shortx8*)(hQ + (size_t)(q0 + qt * 16 + l15) * N1
                                           + kt * 32 + quad * 8);

    floatx4 O[2][4];                    // q-tile x d-tile, full d per wave
    floatx4 Osum[2];                    // row sums via ones-MFMA
#pragma unroll
    for (int qt = 0; qt < 2; ++qt) {
        Osum[qt] = (floatx4)0.f;
#pragma unroll
        for (int dt = 0; dt < 4; ++dt) O[qt][dt] = (floatx4)0.f;
    }

    const shortx4 ones = { (short)0x3F80, (short)0x3F80, (short)0x3F80, (short)0x3F80 };

    const int NT = SEQ / 64;

    // prologue: tile 0 into buffer 0
    int4 ka = *(const int4*)gK, kb = *(const int4*)(gK + 8);
    int4 va = *(const int4*)gV, vb = *(const int4*)(gV + 8);
    *(int4*)(&Ks[0][oL0]) = ka; *(int4*)(&Ks[0][oL1]) = kb;
    *(int4*)(&Vs[0][oL0]) = va; *(int4*)(&Vs[0][oL1]) = vb;
    gK += (size_t)64 * N1; gV += 64;

    for (int it = 0; it < NT; ++it) {
        const int buf = it & 1;
        __syncthreads();                // buf ready (written prev iter/prologue)

        const bool more = (it + 1 < NT);
        if (more) {                     // issue next-tile global loads early
            ka = *(const int4*)gK; kb = *(const int4*)(gK + 8);
            va = *(const int4*)gV; vb = *(const int4*)(gV + 8);
            gK += (size_t)64 * N1; gV += 64;
        }

        const short* Kb = &Ks[buf][0];
        const short* Vb = &Vs[buf][0];

#pragma unroll
        for (int sl = 0; sl < 4; ++sl) {
            // K fragments (b128, swizzled, 8-lane/chunk = b128 floor)
            const short* krow = Kb + (sl * 16 + l15) * 64;
            shortx8 kf0 = *(const shortx8*)(krow + ((quad ^ r7) * 8));
            shortx8 kf1 = *(const shortx8*)(krow + (((quad ^ 4) ^ r7) * 8));
            // V fragments for K=16 PV: B[k=kv=quad*4+i][col=d=l15] contiguous 8B
            shortx4 vf[4];
#pragma unroll
            for (int dt = 0; dt < 4; ++dt)
                vf[dt] = *(const shortx4*)(Vb + (dt * 16 + l15) * 64
                                           + (((sl * 4 + quad) ^ (r7 << 1)) << 2));

            // S^T then exp2 then pack: registers become PV A-fragments
            shortx4 pa[2];
#pragma unroll
            for (int qt = 0; qt < 2; ++qt) {
                floatx4 s = __builtin_amdgcn_mfma_f32_16x16x32_bf16(
                    kf0, qf[qt][0], (floatx4)0.f, 0, 0, 0);
                s = __builtin_amdgcn_mfma_f32_16x16x32_bf16(
                    kf1, qf[qt][1], s, 0, 0, 0);
                const float p0 = EXP2(s[0]);
                const float p1 = EXP2(s[1]);
                const float p2 = EXP2(s[2]);
                const float p3 = EXP2(s[3]);
                union { uint2 u; shortx4 v; } cv;
                cv.u.x = __builtin_amdgcn_perm(fbits(p1), fbits(p0), 0x07060302u);
                cv.u.y = __builtin_amdgcn_perm(fbits(p3), fbits(p2), 0x07060302u);
                pa[qt] = cv.v;
            }

            // O += P @ V ; Osum += P @ 1 (row sums land in (quad*4+r) layout)
#pragma unroll
            for (int qt = 0; qt < 2; ++qt) {
                Osum[qt] = MFMA_K16(pa[qt], ones, Osum[qt]);
#pragma unroll
                for (int dt = 0; dt < 4; ++dt)
                    O[qt][dt] = MFMA_K16(pa[qt], vf[dt], O[qt][dt]);
            }
        }

        if (more) {                     // stage next tile into other buffer
            short* Kn = &Ks[buf ^ 1][0];
            short* Vn = &Vs[buf ^ 1][0];
            *(int4*)(Kn + oL0) = ka; *(int4*)(Kn + oL1) = kb;
            *(int4*)(Vn + oL0) = va; *(int4*)(Vn + oL1) = vb;
        }
    }

    // epilogue: normalize and store (no cross-lane needed; Osum layout matches)
    const size_t obase = ((size_t)n * SEQ + q0) * E_DIM + head * DHEAD;
#pragma unroll
    for (int qt = 0; qt < 2; ++qt)
#pragma unroll
        for (int r = 0; r < 4; ++r) {
            const float inv = 1.f / Osum[qt][r];
            const size_t row = obase + (size_t)(qt * 16 + quad * 4 + r) * E_DIM;
#pragma unroll
            for (int dt = 0; dt < 4; ++dt)
                att[row + dt * 16 + l15] = f2bf(O[qt][dt][r] * inv);
        }
}

// ------------------------------- launch ------------------------------------
extern "C" void kernel_launch(void* const* d_in, const int* in_sizes, int n_in,
                              void* d_out, int out_size, void* d_ws, size_t ws_size,
                              hipStream_t stream)
{
    const float* x  = (const float*)d_in[0];
    const float* W1 = (const float*)d_in[1];
    const float* b1 = (const float*)d_in[2];
    const float* W2 = (const float*)d_in[3];
    const float* b2 = (const float*)d_in[4];
    float* out = (float*)d_out;

    char* ws = (char*)d_ws;
    unsigned short* x_bf  = (unsigned short*)(ws);                    // 16 MB
    unsigned short* W1t   = (unsigned short*)(ws + (16u << 20));      //  6 MB
    unsigned short* W2t   = (unsigned short*)(ws + (22u << 20));      //  2 MB
    unsigned short* h_bf  = (unsigned short*)(ws + (24u << 20));      // 48 MB
    unsigned short* attb  = (unsigned short*)(ws + (72u << 20));      // 16 MB
    unsigned short* Vtw   = (unsigned short*)(ws + (88u << 20));      // 16 MB

    cvt_bf16<<<dim3((M_TOK * E_DIM) / (256 * 8)), 256, 0, stream>>>(x, x_bf);
    cvt_transpose<<<dim3(N1 / 32, E_DIM / 32), dim3(32, 8), 0, stream>>>(W1, W1t, E_DIM, N1);
    cvt_transpose<<<dim3(E_DIM / 32, E_DIM / 32), dim3(32, 8), 0, stream>>>(W2, W2t, E_DIM, E_DIM);

    // h = x@W1+b1 (bf16; Q cols pre-scaled log2(e)/8; V cols also -> Vt transposed)
    gemm_bf16<true, true><<<dim3(N1 / 128, M_TOK / 128), 256, 0, stream>>>(
        (const short*)x_bf, (const short*)W1t, b1, h_bf, Vtw, M_TOK, N1, E_DIM);

    attn_mfma<<<dim3(NB * NHEAD, SEQ / 128), 256, 0, stream>>>(
        (const short*)h_bf, (const short*)Vtw, attb);

    gemm_bf16<false, false><<<dim3(E_DIM / 128, M_TOK / 128), 256, 0, stream>>>(
        (const short*)attb, (const short*)W2t, b2, out, nullptr, M_TOK, E_DIM, E_DIM);
}

// Round 8
// 264.037 us; speedup vs baseline: 1.1370x; 1.0083x over previous
//
#include <hip/hip_runtime.h>
#include <math.h>
#include <stdint.h>
#include <stddef.h>

// ---------------------------------------------------------------------------
// SelfAttention forward, fp32 I/O, bf16 MFMA internally.
// Round 13: attn is LDS-bandwidth-bound (320 KB/CU/tile; model matches r2/r3/
// r6 data). Fix: 64 q rows per wave (qt=4) halves K/V fragment re-reads per
// unit of MFMA work -> 160 KB/CU/tile. Grid 64x8=512 (2 blocks/CU exact),
// LB(256,2) for ~170 VGPR. Attn core otherwise byte-identical v8.
// GEMM keeps round-12's 2-deep vmcnt(8) pipeline (won -11.7 us).
// ---------------------------------------------------------------------------

#define SEQ    2048
#define NB     4
#define E_DIM  1024
#define N1     3072
#define M_TOK  8192
#define NHEAD  16
#define DHEAD  64

typedef __attribute__((ext_vector_type(4))) float    floatx4;
typedef __attribute__((ext_vector_type(8))) short    shortx8;
typedef __attribute__((ext_vector_type(4))) short    shortx4;
typedef __attribute__((ext_vector_type(4))) unsigned short ushortx4;

#if __has_builtin(__builtin_amdgcn_exp2f)
#define EXP2(x) __builtin_amdgcn_exp2f(x)
#else
#define EXP2(x) __expf((x) * 0.6931471805599453f)
#endif

// K=16 bf16 MFMA: A,B = 4x bf16 (2 VGPRs), C/D = 4x f32. A layout
// (row=lane&15, k=quad*4+i) is the exact transpose of the 16x16 C/D layout.
#define MFMA_K16(a, b, c) \
    __builtin_amdgcn_mfma_f32_16x16x16bf16_1k((a), (b), (c), 0, 0, 0)

__device__ __forceinline__ unsigned short f2bf(float f) {
    union { float f; unsigned u; } v; v.f = f;
    unsigned r = (v.u + 0x7FFFu + ((v.u >> 16) & 1u)) >> 16;  // RNE
    return (unsigned short)r;
}
__device__ __forceinline__ unsigned fbits(float f) {
    union { float f; unsigned u; } v; v.f = f; return v.u;
}

__device__ __forceinline__ void gl_lds16(const void* g, void* l) {
    __builtin_amdgcn_global_load_lds(
        (const __attribute__((address_space(1))) unsigned int*)g,
        (__attribute__((address_space(3))) unsigned int*)l, 16, 0, 0);
}

// --------------------------- fp32 -> bf16 convert ---------------------------
__global__ __launch_bounds__(256) void cvt_bf16(
    const float* __restrict__ in, unsigned short* __restrict__ out)
{
    const size_t i = ((size_t)blockIdx.x * 256 + threadIdx.x) * 8;
    float4 a = *(const float4*)(in + i);
    float4 b = *(const float4*)(in + i + 4);
    ushortx4 o0 = { f2bf(a.x), f2bf(a.y), f2bf(a.z), f2bf(a.w) };
    ushortx4 o1 = { f2bf(b.x), f2bf(b.y), f2bf(b.z), f2bf(b.w) };
    *(ushortx4*)(out + i)     = o0;
    *(ushortx4*)(out + i + 4) = o1;
}

// -------------------- fp32 [K][N] -> bf16 transposed [N][K] -----------------
__global__ __launch_bounds__(256) void cvt_transpose(
    const float* __restrict__ W, unsigned short* __restrict__ Wt, int K, int N)
{
    __shared__ unsigned short tile[32][33];
    const int tx = threadIdx.x, ty = threadIdx.y;   // (32, 8)
    const int n0 = blockIdx.x * 32, k0 = blockIdx.y * 32;
#pragma unroll
    for (int r = 0; r < 4; ++r) {
        const int k = ty + r * 8;
        tile[tx][k] = f2bf(W[(size_t)(k0 + k) * N + n0 + tx]);
    }
    __syncthreads();
#pragma unroll
    for (int r = 0; r < 4; ++r) {
        const int n = ty + r * 8;
        Wt[(size_t)(n0 + n) * K + k0 + tx] = tile[n][tx];
    }
}

// --------------------------- bf16 MFMA GEMM --------------------------------
// C[M,N] = A[M,K](bf16) @ Bt[N,K](bf16, pre-transposed) + bias[N](f32).
// BM=BN=128, BK=64, DOUBLE-buffered LDS (64 KB), 2-deep prefetch pipeline:
//   iter t: vmcnt(8) [tile t landed; t+1 in flight] -> s_barrier (publish)
//           -> ds_read frags + 32 MFMA on buf[t] -> s_barrier (buf free)
//           -> global_load_lds tile t+2 into buf[t]
// No vmcnt(0) drain inside the loop. XOR8 swizzle via pre-swizzled GLOBAL
// source chunks (gl_lds dest stays linear) + swizzled ds_read.
// FUSE (gemm1 only): Q columns (col%192 < 64) pre-scaled by log2(e)/8;
// V columns (col%192 >= 128) also stored transposed into Vt[bh][d][s].
template <bool OUT_BF16, bool FUSE>
__global__ __launch_bounds__(256) void gemm_bf16(
    const short* __restrict__ A, const short* __restrict__ Bt,
    const float* __restrict__ bias, void* __restrict__ Cout,
    unsigned short* __restrict__ Vt,
    int M, int N, int K)
{
    __shared__ short As[2][128 * 64];
    __shared__ short Bs[2][128 * 64];

    const int t    = threadIdx.x;
    const int lane = t & 63, w = t >> 6;
    const int quad = lane >> 4, l15 = lane & 15;
    const int bm = blockIdx.y * 128, bn = blockIdx.x * 128;
    const int m0w = (w >> 1) * 64, n0w = (w & 1) * 64;

    // staging: thread t owns row t>>3 (+32 per round), 16B chunk t&7.
    // Global chunk pre-swizzled by row&7; LDS dest linear (lane*16B per wave).
    const int srow   = t >> 3;            // 0..31
    const int schunk = t & 7;             // 16B chunk in 128B row
    const int gch    = schunk ^ (srow & 7);
    const short* Ag = A  + (size_t)(bm + srow) * K + gch * 8;
    const short* Bg = Bt + (size_t)(bn + srow) * K + gch * 8;
    const int sOff = srow * 64 + schunk * 8;   // shorts

    floatx4 acc[4][4];
#pragma unroll
    for (int i = 0; i < 4; ++i)
#pragma unroll
        for (int j = 0; j < 4; ++j) acc[i][j] = (floatx4)0.f;

    const int NK = K >> 6;     // K/64 K-steps

#define GEMM_STAGE(bufi, k0)                                                   \
    {                                                                          \
        _Pragma("unroll")                                                      \
        for (int r = 0; r < 4; ++r) {                                          \
            gl_lds16(Ag + (size_t)(r * 32) * K + (k0), &As[bufi][sOff + r * 32 * 64]); \
            gl_lds16(Bg + (size_t)(r * 32) * K + (k0), &Bs[bufi][sOff + r * 32 * 64]); \
        }                                                                      \
    }

    // prologue: tiles 0 and 1 in flight (16 outstanding loads)
    GEMM_STAGE(0, 0);
    GEMM_STAGE(1, 64);

    for (int kt = 0; kt < NK; ++kt) {
        const int buf = kt & 1;
        // wait for tile kt (8 newest = tile kt+1 may stay in flight)
        if (kt + 1 < NK) asm volatile("s_waitcnt vmcnt(8)" ::: "memory");
        else             asm volatile("s_waitcnt vmcnt(0)" ::: "memory");
        __builtin_amdgcn_sched_barrier(0);
        __builtin_amdgcn_s_barrier();          // publish tile kt to all waves
        __builtin_amdgcn_sched_barrier(0);

#pragma unroll
        for (int kk = 0; kk < 2; ++kk) {
            shortx8 af[4], bf[4];
#pragma unroll
            for (int mi = 0; mi < 4; ++mi)
                af[mi] = *(const shortx8*)(&As[buf][(m0w + mi * 16 + l15) * 64
                                           + (((kk * 4 + quad) ^ (l15 & 7)) * 8)]);
#pragma unroll
            for (int ni = 0; ni < 4; ++ni)
                bf[ni] = *(const shortx8*)(&Bs[buf][(n0w + ni * 16 + l15) * 64
                                           + (((kk * 4 + quad) ^ (l15 & 7)) * 8)]);
#pragma unroll
            for (int mi = 0; mi < 4; ++mi)
#pragma unroll
                for (int ni = 0; ni < 4; ++ni)
                    acc[mi][ni] = __builtin_amdgcn_mfma_f32_16x16x32_bf16(
                        af[mi], bf[ni], acc[mi][ni], 0, 0, 0);
        }

        __builtin_amdgcn_sched_barrier(0);
        __builtin_amdgcn_s_barrier();          // all waves done reading buf
        __builtin_amdgcn_sched_barrier(0);
        if (kt + 2 < NK) GEMM_STAGE(buf, (kt + 2) * 64);
    }
#undef GEMM_STAGE

    float bv[4];
#pragma unroll
    for (int ni = 0; ni < 4; ++ni) bv[ni] = bias[bn + n0w + ni * 16 + l15];

#pragma unroll
    for (int ni = 0; ni < 4; ++ni) {
        const int col   = bn + n0w + ni * 16 + l15;
        const int cm    = col % 192;      // wave-uniform block (no divergence)
        const int vhead = col / 192;
#pragma unroll
        for (int mi = 0; mi < 4; ++mi) {
            const int row0 = bm + m0w + mi * 16 + quad * 4;
            float v[4];
#pragma unroll
            for (int r = 0; r < 4; ++r) v[r] = acc[mi][ni][r] + bv[ni];
            if (OUT_BF16) {
                if (FUSE && cm < DHEAD) {
#pragma unroll
                    for (int r = 0; r < 4; ++r) v[r] *= 0.18033688011112042f;  // log2(e)/8
                }
                unsigned short* H = (unsigned short*)Cout;
#pragma unroll
                for (int r = 0; r < 4; ++r)
                    H[(size_t)(row0 + r) * N + col] = f2bf(v[r]);
                if (FUSE && cm >= 2 * DHEAD) {
                    const int nb = row0 >> 11;       // batch
                    const int s  = row0 & 2047;
                    const int d  = cm - 2 * DHEAD;
                    ushortx4 pk = { f2bf(v[0]), f2bf(v[1]), f2bf(v[2]), f2bf(v[3]) };
                    *(ushortx4*)(Vt + ((size_t)(nb * NHEAD + vhead) * DHEAD + d) * SEQ + s) = pk;
                }
            } else {
                float* C = (float*)Cout;
#pragma unroll
                for (int r = 0; r < 4; ++r)
                    C[(size_t)(row0 + r) * N + col] = v[r];
            }
        }
    }
}

// ------------------------- MFMA flash attention v12 -------------------------
// v8 core with qt=4: 256 thr = 4 waves; wave w owns q rows q0+w*64 .. +63,
// full d=64. K/V fragment LDS reads are q-independent, so 64 q/wave halves
// LDS read traffic per MFMA (the measured bottleneck). Grid (64 bh, 8) = 512
// blocks = 2/CU; LB(256,2) gives the ~170 VGPR this needs.
__global__ __launch_bounds__(256, 2) void attn_mfma(
    const short* __restrict__ h, const short* __restrict__ Vt,
    unsigned short* __restrict__ att)
{
    __shared__ short Ks[2][64 * 64];    // [kv][d], XOR8 16B-chunk swizzle
    __shared__ short Vs[2][64 * 64];    // [d][kv], XOR8 8B-chunk swizzle

    const int t    = threadIdx.x;
    const int lane = t & 63, w = t >> 6;
    const int quad = lane >> 4, l15 = lane & 15;
    const int r7   = l15 & 7;
    const int bh = blockIdx.x, n = bh >> 4, head = bh & 15;
    const int q0 = blockIdx.y * 256 + w * 64;

    const short* hQ  = h + (size_t)n * SEQ * N1 + head * (3 * DHEAD);
    const short* hK  = hQ + DHEAD;
    const short* Vtb = Vt + (size_t)bh * DHEAD * SEQ;

    // staging: thread t owns row t>>2, 16B chunks (t&3)*2 and +1 (K and V)
    const int srow = t >> 2;
    const int sc0  = (t & 3) * 2;
    const int sk   = srow & 7;
    const short* gK = hK  + (size_t)srow * N1  + sc0 * 8;
    const short* gV = Vtb + (size_t)srow * SEQ + sc0 * 8;
    const int oL0 = srow * 64 + ((sc0    ) ^ sk) * 8;
    const int oL1 = srow * 64 + ((sc0 + 1) ^ sk) * 8;

    // Q fragments: 64 rows per wave, hoisted once (32 VGPR)
    shortx8 qf[4][2];
#pragma unroll
    for (int qt = 0; qt < 4; ++qt)
#pragma unroll
        for (int kt = 0; kt < 2; ++kt)
            qf[qt][kt] = *(const shortx8*)(hQ + (size_t)(q0 + qt * 16 + l15) * N1
                                           + kt * 32 + quad * 8);

    floatx4 O[4][4];                    // q-tile x d-tile, full d per wave
    floatx4 Osum[4];                    // row sums via ones-MFMA
#pragma unroll
    for (int qt = 0; qt < 4; ++qt) {
        Osum[qt] = (floatx4)0.f;
#pragma unroll
        for (int dt = 0; dt < 4; ++dt) O[qt][dt] = (floatx4)0.f;
    }

    const shortx4 ones = { (short)0x3F80, (short)0x3F80, (short)0x3F80, (short)0x3F80 };

    const int NT = SEQ / 64;

    // prologue: tile 0 into buffer 0
    int4 ka = *(const int4*)gK, kb = *(const int4*)(gK + 8);
    int4 va = *(const int4*)gV, vb = *(const int4*)(gV + 8);
    *(int4*)(&Ks[0][oL0]) = ka; *(int4*)(&Ks[0][oL1]) = kb;
    *(int4*)(&Vs[0][oL0]) = va; *(int4*)(&Vs[0][oL1]) = vb;
    gK += (size_t)64 * N1; gV += 64;

    for (int it = 0; it < NT; ++it) {
        const int buf = it & 1;
        __syncthreads();                // buf ready (written prev iter/prologue)

        const bool more = (it + 1 < NT);
        if (more) {                     // issue next-tile global loads early
            ka = *(const int4*)gK; kb = *(const int4*)(gK + 8);
            va = *(const int4*)gV; vb = *(const int4*)(gV + 8);
            gK += (size_t)64 * N1; gV += 64;
        }

        const short* Kb = &Ks[buf][0];
        const short* Vb = &Vs[buf][0];

#pragma unroll
        for (int sl = 0; sl < 4; ++sl) {
            // K fragments (b128, swizzled, 8-lane/chunk = b128 floor)
            const short* krow = Kb + (sl * 16 + l15) * 64;
            shortx8 kf0 = *(const shortx8*)(krow + ((quad ^ r7) * 8));
            shortx8 kf1 = *(const shortx8*)(krow + (((quad ^ 4) ^ r7) * 8));
            // V fragments for K=16 PV: B[k=kv=quad*4+i][col=d=l15] contiguous 8B
            shortx4 vf[4];
#pragma unroll
            for (int dt = 0; dt < 4; ++dt)
                vf[dt] = *(const shortx4*)(Vb + (dt * 16 + l15) * 64
                                           + (((sl * 4 + quad) ^ (r7 << 1)) << 2));

            // S^T then exp2 then pack: registers become PV A-fragments
            shortx4 pa[4];
#pragma unroll
            for (int qt = 0; qt < 4; ++qt) {
                floatx4 s = __builtin_amdgcn_mfma_f32_16x16x32_bf16(
                    kf0, qf[qt][0], (floatx4)0.f, 0, 0, 0);
                s = __builtin_amdgcn_mfma_f32_16x16x32_bf16(
                    kf1, qf[qt][1], s, 0, 0, 0);
                const float p0 = EXP2(s[0]);
                const float p1 = EXP2(s[1]);
                const float p2 = EXP2(s[2]);
                const float p3 = EXP2(s[3]);
                union { uint2 u; shortx4 v; } cv;
                cv.u.x = __builtin_amdgcn_perm(fbits(p1), fbits(p0), 0x07060302u);
                cv.u.y = __builtin_amdgcn_perm(fbits(p3), fbits(p2), 0x07060302u);
                pa[qt] = cv.v;
            }

            // O += P @ V ; Osum += P @ 1 (row sums land in (quad*4+r) layout)
#pragma unroll
            for (int qt = 0; qt < 4; ++qt) {
                Osum[qt] = MFMA_K16(pa[qt], ones, Osum[qt]);
#pragma unroll
                for (int dt = 0; dt < 4; ++dt)
                    O[qt][dt] = MFMA_K16(pa[qt], vf[dt], O[qt][dt]);
            }
        }

        if (more) {                     // stage next tile into other buffer
            short* Kn = &Ks[buf ^ 1][0];
            short* Vn = &Vs[buf ^ 1][0];
            *(int4*)(Kn + oL0) = ka; *(int4*)(Kn + oL1) = kb;
            *(int4*)(Vn + oL0) = va; *(int4*)(Vn + oL1) = vb;
        }
    }

    // epilogue: normalize and store (no cross-lane needed; Osum layout matches)
    const size_t obase = ((size_t)n * SEQ + q0) * E_DIM + head * DHEAD;
#pragma unroll
    for (int qt = 0; qt < 4; ++qt)
#pragma unroll
        for (int r = 0; r < 4; ++r) {
            const float inv = 1.f / Osum[qt][r];
            const size_t row = obase + (size_t)(qt * 16 + quad * 4 + r) * E_DIM;
#pragma unroll
            for (int dt = 0; dt < 4; ++dt)
                att[row + dt * 16 + l15] = f2bf(O[qt][dt][r] * inv);
        }
}

// ------------------------------- launch ------------------------------------
extern "C" void kernel_launch(void* const* d_in, const int* in_sizes, int n_in,
                              void* d_out, int out_size, void* d_ws, size_t ws_size,
                              hipStream_t stream)
{
    const float* x  = (const float*)d_in[0];
    const float* W1 = (const float*)d_in[1];
    const float* b1 = (const float*)d_in[2];
    const float* W2 = (const float*)d_in[3];
    const float* b2 = (const float*)d_in[4];
    float* out = (float*)d_out;

    char* ws = (char*)d_ws;
    unsigned short* x_bf  = (unsigned short*)(ws);                    // 16 MB
    unsigned short* W1t   = (unsigned short*)(ws + (16u << 20));      //  6 MB
    unsigned short* W2t   = (unsigned short*)(ws + (22u << 20));      //  2 MB
    unsigned short* h_bf  = (unsigned short*)(ws + (24u << 20));      // 48 MB
    unsigned short* attb  = (unsigned short*)(ws + (72u << 20));      // 16 MB
    unsigned short* Vtw   = (unsigned short*)(ws + (88u << 20));      // 16 MB

    cvt_bf16<<<dim3((M_TOK * E_DIM) / (256 * 8)), 256, 0, stream>>>(x, x_bf);
    cvt_transpose<<<dim3(N1 / 32, E_DIM / 32), dim3(32, 8), 0, stream>>>(W1, W1t, E_DIM, N1);
    cvt_transpose<<<dim3(E_DIM / 32, E_DIM / 32), dim3(32, 8), 0, stream>>>(W2, W2t, E_DIM, E_DIM);

    // h = x@W1+b1 (bf16; Q cols pre-scaled log2(e)/8; V cols also -> Vt transposed)
    gemm_bf16<true, true><<<dim3(N1 / 128, M_TOK / 128), 256, 0, stream>>>(
        (const short*)x_bf, (const short*)W1t, b1, h_bf, Vtw, M_TOK, N1, E_DIM);

    attn_mfma<<<dim3(NB * NHEAD, SEQ / 256), 256, 0, stream>>>(
        (const short*)h_bf, (const short*)Vtw, attb);

    gemm_bf16<false, false><<<dim3(E_DIM / 128, M_TOK / 128), 256, 0, stream>>>(
        (const short*)attb, (const short*)W2t, b2, out, nullptr, M_TOK, E_DIM, E_DIM);
}